// Round 4
// baseline (7945.066 us; speedup 1.0000x reference)
//
#include <hip/hip_runtime.h>
#include <hip/hip_bf16.h>

// CrossGRU round 4: fragment-major packed MFMA GRU (round-3 design, MFMA macro fixed).
// - Weights packed once/call into MFMA B-fragment order (hi/lo bf16).
// - Recurrent state stored as bf16 hi/lo pair in A-fragment order (exact to 2^-17).
// - K-folded GEMMs: L0 [h|x]*[Whh|Wih]^T (K=320), L1 [h1|h0]*[Whh1|Wih1]^T (K=512).
// - 256 blocks (1/CU): 128/layer, each 128 rows x 32 channels; LDS double-buffered
//   staging via global_load_lds width=16; all fragment loads are 1KB coalesced.
// - proj_gemm: LDS-tiled register-blocked fp32 GEMM for the three projections.

#define HH  256
#define TT  128
#define INP 64
#define KH  8   // h-part kc count (256/32)

typedef float f32x4 __attribute__((ext_vector_type(4)));
typedef short bf16x8 __attribute__((ext_vector_type(8)));

#define MFMA(A,B,C) __builtin_amdgcn_mfma_f32_16x16x32_bf16((A),(B),(C),0,0,0)

__device__ __forceinline__ float bf2f(unsigned short s) {
    unsigned u = ((unsigned)s) << 16;
    float f; __builtin_memcpy(&f, &u, 4); return f;
}
__device__ __forceinline__ unsigned short f2bf(float f) {
    unsigned u; __builtin_memcpy(&u, &f, 4);
    unsigned r = (u + 0x7FFFu + ((u >> 16) & 1u)) >> 16;
    return (unsigned short)r;
}

__device__ __forceinline__ void gload_lds(const unsigned short* src, short* dst) {
    __builtin_amdgcn_global_load_lds(
        (const __attribute__((address_space(1))) unsigned int*)src,
        (__attribute__((address_space(3))) unsigned int*)dst, 16, 0, 0);
}

// fragment-major index for element (row r, col k) of a tile-major tensor with K cols:
// idx = (r>>4)*(K*16) + (k>>5)*512 + ((k>>3)&3)*128 + (r&15)*8 + (k&7)

// ---- pack weights: Wcomb = [Whh(256) | Wih(Kin)] -> frag-major hi/lo ----
__global__ void pack_w(const float* __restrict__ Whh, const float* __restrict__ Wih,
                       int Kin, int Kw, unsigned short* __restrict__ FBhi,
                       unsigned short* __restrict__ FBlo, int total)
{
    int idx = blockIdx.x * 256 + threadIdx.x;
    if (idx >= total) return;
    int n = idx / Kw, k = idx - n * Kw;
    float v = (k < 256) ? Whh[n * 256 + k] : Wih[n * Kin + (k - 256)];
    int dst = (n >> 4) * (Kw * 16) + (k >> 5) * 512 + ((k >> 3) & 3) * 128 + (n & 15) * 8 + (k & 7);
    unsigned short h = f2bf(v);
    FBhi[dst] = h;
    FBlo[dst] = f2bf(v - bf2f(h));
}

// ---- pack x: x[m][t][k] fp32 -> per-t frag-major bf16 (hi only) ----
__global__ void pack_x(const float* __restrict__ x, unsigned short* __restrict__ FXhi)
{
    int idx = blockIdx.x * 256 + threadIdx.x;  // 2048*128*64 = 16777216
    int k = idx & 63;
    int t = (idx >> 6) & 127;
    int m = idx >> 13;
    int dst = t * 131072 + (m >> 4) * 1024 + (k >> 5) * 512 + ((k >> 3) & 3) * 128 + (m & 15) * 8 + (k & 7);
    FXhi[dst] = f2bf(x[idx]);
}

// ---------------- GRU step ----------------
// 256 blocks: [0,128)=layer0, [128,256)=layer1. Block: 128 rows x 32 channels.
// mb = m-block (16), cb = c-block (8). Waves 2x2: wm = m-half, wn = c-sub (16 ch).
// LDS chunk per kc: A[8 mt][hi/lo][512] + B[6 ntl][hi/lo][512] = 28 KB, double-buffered.
__global__ __launch_bounds__(256) void gru_step(
    const unsigned short* __restrict__ H0rhi, const unsigned short* __restrict__ H0rlo,
    unsigned short* __restrict__ H0whi, unsigned short* __restrict__ H0wlo,
    const unsigned short* __restrict__ H1rhi, const unsigned short* __restrict__ H1rlo,
    unsigned short* __restrict__ H1whi, unsigned short* __restrict__ H1wlo,
    const unsigned short* __restrict__ FXhi,
    const unsigned short* __restrict__ FB0hi, const unsigned short* __restrict__ FB0lo,
    const unsigned short* __restrict__ FB1hi, const unsigned short* __restrict__ FB1lo,
    const float* __restrict__ bih0, const float* __restrict__ bhh0,
    const float* __restrict__ bih1, const float* __restrict__ bhh1,
    float* __restrict__ S1f, int step)
{
    __shared__ short lds[2][14336];
    const int layer = blockIdx.x >> 7;
    if (!layer && step >= TT) return;
    if (layer && step == 0) return;
    const int bid = blockIdx.x & 127;
    const int mb = bid >> 3;
    const int cb = bid & 7;
    const int tid = threadIdx.x;
    const int w = tid >> 6, lane = tid & 63;
    const int wm = w >> 1, wn = w & 1;
    const int l15 = lane & 15, q = lane >> 4;
    const int mb8 = mb * 8;

    const unsigned short* Ahi_h = layer ? H1rhi : H0rhi;
    const unsigned short* Alo_h = layer ? H1rlo : H0rlo;
    const unsigned short* Ahi_x = layer ? H0rhi : (FXhi + step * 131072);
    const unsigned short* Alo_x = layer ? H0rlo : (FXhi + step * 131072);  // L0: dup (2-term)
    const int xstride = layer ? 4096 : 1024;
    unsigned short* Whi_out = layer ? H1whi : H0whi;
    unsigned short* Wlo_out = layer ? H1wlo : H0wlo;
    const unsigned short* Bhi = layer ? FB1hi : FB0hi;
    const unsigned short* Blo = layer ? FB1lo : FB0lo;
    const float* bih = layer ? bih1 : bih0;
    const float* bhh = layer ? bhh1 : bhh0;
    const int Kw = layer ? 512 : 320;
    const int nkc = Kw >> 5;

    f32x4 ar[4], az[4], anh[4], anx[4];
#pragma unroll
    for (int i = 0; i < 4; ++i) {
        ar[i] = (f32x4){0.f,0.f,0.f,0.f}; az[i] = (f32x4){0.f,0.f,0.f,0.f};
        anh[i] = (f32x4){0.f,0.f,0.f,0.f}; anx[i] = (f32x4){0.f,0.f,0.f,0.f};
    }

    auto stage = [&](int kc, int bufi) {
        short* dst0 = &lds[bufi][0];
        for (int i = w; i < 28; i += 4) {
            const unsigned short* src;
            if (i < 16) {
                int mt = i >> 1, s = i & 1;
                if (kc < KH) {
                    src = (s ? Alo_h : Ahi_h) + (mb8 + mt) * 4096 + kc * 512;
                } else {
                    src = (s ? Alo_x : Ahi_x) + (mb8 + mt) * xstride + (kc - KH) * 512;
                }
            } else {
                int j = i - 16, ntl = j >> 1, s = j & 1;
                int ntg = (ntl >> 1) * 16 + cb * 2 + (ntl & 1);
                src = (s ? Blo : Bhi) + ntg * (Kw * 16) + kc * 512;
            }
            gload_lds(src + lane * 8, dst0 + i * 512);
        }
    };

    stage(0, 0);
    __syncthreads();

    for (int kc = 0; kc < nkc; ++kc) {
        if (kc + 1 < nkc) stage(kc + 1, (kc + 1) & 1);
        const short* bp = &lds[kc & 1][0];
        bf16x8 a[4][2], bw[3][2];
#pragma unroll
        for (int mt = 0; mt < 4; ++mt) {
#pragma unroll
            for (int s = 0; s < 2; ++s)
                a[mt][s] = *(const bf16x8*)(bp + ((wm * 4 + mt) * 2 + s) * 512 + lane * 8);
        }
#pragma unroll
        for (int g = 0; g < 3; ++g) {
#pragma unroll
            for (int s = 0; s < 2; ++s)
                bw[g][s] = *(const bf16x8*)(bp + 8192 + ((g * 2 + wn) * 2 + s) * 512 + lane * 8);
        }
        const bool hpart = (kc < KH);
        const bool full3 = layer || hpart;   // L0 x-part: 2-term (no state-lo)

#pragma unroll
        for (int mt = 0; mt < 4; ++mt) {
            ar[mt] = MFMA(a[mt][0], bw[0][0], ar[mt]);
            ar[mt] = MFMA(a[mt][0], bw[0][1], ar[mt]);
            az[mt] = MFMA(a[mt][0], bw[1][0], az[mt]);
            az[mt] = MFMA(a[mt][0], bw[1][1], az[mt]);
        }
        if (full3) {
#pragma unroll
            for (int mt = 0; mt < 4; ++mt) {
                ar[mt] = MFMA(a[mt][1], bw[0][0], ar[mt]);
                az[mt] = MFMA(a[mt][1], bw[1][0], az[mt]);
            }
        }
        if (hpart) {
#pragma unroll
            for (int mt = 0; mt < 4; ++mt) {
                anh[mt] = MFMA(a[mt][0], bw[2][0], anh[mt]);
                anh[mt] = MFMA(a[mt][0], bw[2][1], anh[mt]);
                anh[mt] = MFMA(a[mt][1], bw[2][0], anh[mt]);
            }
        } else if (full3) {
#pragma unroll
            for (int mt = 0; mt < 4; ++mt) {
                anx[mt] = MFMA(a[mt][0], bw[2][0], anx[mt]);
                anx[mt] = MFMA(a[mt][0], bw[2][1], anx[mt]);
                anx[mt] = MFMA(a[mt][1], bw[2][0], anx[mt]);
            }
        } else {
#pragma unroll
            for (int mt = 0; mt < 4; ++mt) {
                anx[mt] = MFMA(a[mt][0], bw[2][0], anx[mt]);
                anx[mt] = MFMA(a[mt][0], bw[2][1], anx[mt]);
            }
        }
        __syncthreads();
    }

    // ---- gates + state write (C/D: col=l15 -> channel, row=q*4+rg -> m) ----
    const int c = cb * 32 + wn * 16 + l15;
    const float brb = bih[c] + bhh[c];
    const float bzb = bih[256 + c] + bhh[256 + c];
    const float bni = bih[512 + c];
    const float bnh = bhh[512 + c];
    const int cfr = (c >> 5) * 512 + ((c >> 3) & 3) * 128 + (c & 7);
#pragma unroll
    for (int mt = 0; mt < 4; ++mt) {
        const int mtg = mb8 + wm * 4 + mt;
        const int fbase = mtg * 4096 + cfr;
#pragma unroll
        for (int rg = 0; rg < 4; ++rg) {
            const int mi = q * 4 + rg;
            const int fidx = fbase + mi * 8;
            const float ho = bf2f(Ahi_h[fidx]) + bf2f(Alo_h[fidx]);
            const float rr = 1.f / (1.f + expf(-(ar[mt][rg] + brb)));
            const float zz = 1.f / (1.f + expf(-(az[mt][rg] + bzb)));
            const float nn = tanhf(anx[mt][rg] + bni + rr * (anh[mt][rg] + bnh));
            const float hn = (1.f - zz) * nn + zz * ho;
            const unsigned short hb = f2bf(hn);
            Whi_out[fidx] = hb;
            Wlo_out[fidx] = f2bf(hn - bf2f(hb));
            if (layer) S1f[(mtg * 16 + mi) * 256 + c] = hn;
        }
    }
}

// ---------------- epilogue ----------------

// Tiled GEMM: out[p][h][l][d] = S[l,:]·W_p[h,:,d] + b. Block = (p,h) x 64-l tile.
__global__ __launch_bounds__(256) void proj_gemm(const float* __restrict__ S,
    const float* __restrict__ Wk, const float* __restrict__ bk,
    const float* __restrict__ Wv, const float* __restrict__ bv,
    const float* __restrict__ Wq, const float* __restrict__ bq,
    float* __restrict__ ok, float* __restrict__ ov, float* __restrict__ oq)
{
    __shared__ float sT[256][65];
    const int bid = blockIdx.x;            // 192 = 3p * 2h * 32lt
    const int p = bid >> 6;
    const int h = (bid >> 5) & 1;
    const int l0 = (bid & 31) * 64;
    const int tid = threadIdx.x;
    const float* W = (p == 0) ? Wk : ((p == 1) ? Wv : Wq);
    const float* b = (p == 0) ? bk : ((p == 1) ? bv : bq);
    float* o = (p == 0) ? ok : ((p == 1) ? ov : oq);

    for (int e = tid; e < 64 * 256; e += 256) {
        int k = e & 255, l = e >> 8;
        sT[k][l] = S[(l0 + l) * 256 + k];
    }
    __syncthreads();

    const int dg = tid & 15, lg = tid >> 4;     // 8 d's, 4 l's per thread
    const int d0 = dg * 8;
    const float* Wp = W + h * 32768 + d0;
    float acc[4][8];
#pragma unroll
    for (int i = 0; i < 4; ++i)
#pragma unroll
        for (int j = 0; j < 8; ++j) acc[i][j] = 0.f;

    for (int k = 0; k < 256; ++k) {
        f32x4 sv = *(const f32x4*)&sT[k][lg * 4];
        f32x4 w0 = *(const f32x4*)(Wp + k * 128);
        f32x4 w1 = *(const f32x4*)(Wp + k * 128 + 4);
#pragma unroll
        for (int i = 0; i < 4; ++i) {
#pragma unroll
            for (int j = 0; j < 4; ++j) {
                acc[i][j]     += sv[i] * w0[j];
                acc[i][4 + j] += sv[i] * w1[j];
            }
        }
    }
#pragma unroll
    for (int i = 0; i < 4; ++i) {
        float* op = o + (h * 2048 + l0 + lg * 4 + i) * 128 + d0;
#pragma unroll
        for (int j = 0; j < 8; ++j) op[j] = acc[i][j] + b[h * 128 + d0 + j];
    }
}

// small proj for Bm (M=30, k/v only)
__global__ void proj3_kernel(const float* __restrict__ A, int M,
    const float* __restrict__ Wk, const float* __restrict__ bk,
    const float* __restrict__ Wv, const float* __restrict__ bv,
    float* __restrict__ ok, float* __restrict__ ov)
{
    int idx = blockIdx.x * 256 + threadIdx.x;
    if (idx >= 2 * 2 * M * 128) return;
    int d = idx & 127;
    int rest = idx >> 7;
    int l = rest % M;
    int ph = rest / M;
    int h = ph & 1, p = ph >> 1;
    const float* W = (p == 0) ? Wk : Wv;
    const float* b = (p == 0) ? bk : bv;
    float* o = (p == 0) ? ok : ov;
    float accv = b[h * 128 + d];
    const float* a = A + l * 256;
    const float* wp = W + h * (256 * 128) + d;
    for (int j = 0; j < 256; ++j) accv += a[j] * wp[j * 128];
    o[(h * M + l) * 128 + d] = accv;
}

__global__ void projR_kernel(const float* __restrict__ R,
    const float* __restrict__ Wq, const float* __restrict__ bq,
    float* __restrict__ oq)
{
    int idx = blockIdx.x * 256 + threadIdx.x;
    if (idx >= 2 * 30 * 128) return;
    int d = idx & 127;
    int rest = idx >> 7;
    int l = rest % 30;
    int h = rest / 30;
    float a = bq[h * 128 + d];
    const float* r = R + l * 256;
    const float* wp = Wq + h * 32768 + d;
    for (int j = 0; j < 256; ++j) a += r[j] * wp[j * 128];
    oq[(h * 30 + l) * 128 + d] = a;
}

__global__ void scores1_kernel(const float* __restrict__ qhR, const float* __restrict__ kh,
                               float* __restrict__ s1)
{
    int idx = blockIdx.x * 256 + threadIdx.x;
    if (idx >= 2 * 30 * 2048) return;
    int k = idx & 2047;
    int rest = idx >> 11;
    int i = rest % 30;
    int h = rest / 30;
    const f32x4* qp = (const f32x4*)(qhR + (h * 30 + i) * 128);
    const f32x4* kp = (const f32x4*)(kh + (h * 2048 + k) * 128);
    float acc = 0.f;
    for (int dd = 0; dd < 32; ++dd) {
        f32x4 a = qp[dd], b = kp[dd];
        acc += a[0] * b[0] + a[1] * b[1] + a[2] * b[2] + a[3] * b[3];
    }
    s1[idx] = acc * 0.08838834764831845f;
}

__global__ void softmax1_kernel(float* __restrict__ s1)
{
    __shared__ float red[256];
    float* p = s1 + blockIdx.x * 2048;
    int tid = threadIdx.x;
    float mx = -1e30f;
    for (int k = tid; k < 2048; k += 256) mx = fmaxf(mx, p[k]);
    red[tid] = mx; __syncthreads();
    for (int s = 128; s > 0; s >>= 1) { if (tid < s) red[tid] = fmaxf(red[tid], red[tid + s]); __syncthreads(); }
    mx = red[0]; __syncthreads();
    float sum = 0.f;
    for (int k = tid; k < 2048; k += 256) { float e = expf(p[k] - mx); p[k] = e; sum += e; }
    red[tid] = sum; __syncthreads();
    for (int s = 128; s > 0; s >>= 1) { if (tid < s) red[tid] += red[tid + s]; __syncthreads(); }
    float inv = 1.f / red[0];
    for (int k = tid; k < 2048; k += 256) p[k] *= inv;
}

__global__ void o1_kernel(const float* __restrict__ p1, const float* __restrict__ vh,
                          float* __restrict__ Bm)
{
    int row = blockIdx.x;            // h*30+i
    int h = row / 30;
    int i = row % 30;
    int d = threadIdx.x;             // 128
    const float* pp = p1 + row * 2048;
    const float* vp = vh + h * 2048 * 128 + d;
    float acc = 0.f;
    for (int k = 0; k < 2048; ++k) acc += pp[k] * vp[k * 128];
    Bm[i * 256 + h * 128 + d] = acc;
}

__global__ __launch_bounds__(256) void attn2_kernel(
    const float* __restrict__ qh2, const float* __restrict__ kh2, const float* __restrict__ vh2,
    const float* __restrict__ S, const float* __restrict__ Wg,
    const float* __restrict__ bg, float* __restrict__ Smix)
{
    __shared__ float ks[2 * 30 * 129];
    __shared__ float qred[256];
    __shared__ float ps[64];
    int l = blockIdx.x;
    int tid = threadIdx.x;
    for (int idx = tid; idx < 2 * 30 * 128; idx += 256) {
        int hh = idx / 3840; int rem = idx - hh * 3840;
        int j = rem >> 7; int d = rem & 127;
        ks[(hh * 30 + j) * 129 + d] = kh2[idx];
    }
    int h = tid >> 7, d = tid & 127;
    qred[tid] = qh2[(h * 2048 + l) * 128 + d];
    __syncthreads();
    int w = tid >> 6, lane = tid & 63;
    if (w < 2 && lane < 32) {
        float sc = -1e30f;
        if (lane < 30) {
            const float* qp = qred + w * 128;
            float a = 0.f;
            for (int dd = 0; dd < 128; ++dd) a += qp[dd] * ks[(w * 30 + lane) * 129 + dd];
            sc = a * 0.08838834764831845f;
        }
        float mx = sc;
        for (int m = 16; m > 0; m >>= 1) mx = fmaxf(mx, __shfl_xor(mx, m, 32));
        float e = (lane < 30) ? expf(sc - mx) : 0.f;
        float sm = e;
        for (int m = 16; m > 0; m >>= 1) sm += __shfl_xor(sm, m, 32);
        ps[w * 32 + lane] = e / sm;
    }
    __syncthreads();
    float o = 0.f;
    const float* vp = vh2 + h * 3840 + d;
    for (int j = 0; j < 30; ++j) o += ps[h * 32 + j] * vp[j * 128];
    float sl = S[l * 256 + tid];
    qred[tid] = sl * Wg[tid];
    __syncthreads();
    for (int s = 128; s > 0; s >>= 1) { if (tid < s) qred[tid] += qred[tid + s]; __syncthreads(); }
    float alpha = 1.f / (1.f + expf(-(qred[0] + bg[0])));
    Smix[l * 256 + tid] = alpha * o + (1.f - alpha) * sl;
}

__global__ void w1t_kernel(const float* __restrict__ W1, float* __restrict__ W1T)
{
    int idx = blockIdx.x * 256 + threadIdx.x;  // 65536
    int j = idx & 255, c = idx >> 8;
    W1T[j * 256 + c] = W1[c * 256 + j];
}

__global__ void mlp_kernel(const float* __restrict__ Smix, const float* __restrict__ W1T,
                           const float* __restrict__ b1, float* __restrict__ S2)
{
    int idx = blockIdx.x * 256 + threadIdx.x;  // l*256+c
    int c = idx & 255; int l = idx >> 8;
    const float* a = Smix + l * 256;
    float acc = b1[c];
    for (int j = 0; j < 256; ++j) acc += a[j] * W1T[j * 256 + c];
    float v = fmaxf(acc, 0.f);
    S2[idx] = v + a[c];
}

__global__ void y_kernel(const float* __restrict__ S2, const float* __restrict__ W2,
                         const float* __restrict__ b2, float* __restrict__ y)
{
    __shared__ float red[256];
    int l = blockIdx.x; int tid = threadIdx.x;
    red[tid] = S2[l * 256 + tid] * W2[tid];
    __syncthreads();
    for (int s = 128; s > 0; s >>= 1) { if (tid < s) red[tid] += red[tid + s]; __syncthreads(); }
    if (tid == 0) y[l] = red[0] + b2[0];
}

__global__ void norm_kernel(const float* __restrict__ y, float* __restrict__ out)
{
    __shared__ float r1[1024], r2[1024];
    int tid = threadIdx.x;
    float s1v = 0.f, s2v = 0.f;
    for (int idx = tid; idx < 2048; idx += 1024) { float v = y[idx]; s1v += v; s2v += v * v; }
    r1[tid] = s1v; r2[tid] = s2v; __syncthreads();
    for (int s = 512; s > 0; s >>= 1) {
        if (tid < s) { r1[tid] += r1[tid + s]; r2[tid] += r2[tid + s]; }
        __syncthreads();
    }
    float mean = r1[0] / 2048.f;
    float var = fmaxf((r2[0] - 2048.f * mean * mean) / 2047.f, 0.f);
    float inv = 1.f / (sqrtf(var) + 1e-8f);
    for (int idx = tid; idx < 2048; idx += 1024)
        out[idx] = (y[idx] - mean) * inv;
}

extern "C" void kernel_launch(void* const* d_in, const int* in_sizes, int n_in,
                              void* d_out, int out_size, void* d_ws, size_t ws_size,
                              hipStream_t stream)
{
    const float* x    = (const float*)d_in[0];
    const float* Wih0 = (const float*)d_in[1];
    const float* Whh0 = (const float*)d_in[2];
    const float* bih0 = (const float*)d_in[3];
    const float* bhh0 = (const float*)d_in[4];
    const float* Wih1 = (const float*)d_in[5];
    const float* Whh1 = (const float*)d_in[6];
    const float* bih1 = (const float*)d_in[7];
    const float* bhh1 = (const float*)d_in[8];
    const float* Wq   = (const float*)d_in[9];
    const float* bq   = (const float*)d_in[10];
    const float* Wk   = (const float*)d_in[11];
    const float* bk   = (const float*)d_in[12];
    const float* Wv   = (const float*)d_in[13];
    const float* bv   = (const float*)d_in[14];
    const float* R    = (const float*)d_in[15];
    const float* Wg   = (const float*)d_in[16];
    const float* bg   = (const float*)d_in[17];
    const float* W1   = (const float*)d_in[18];
    const float* b1   = (const float*)d_in[19];
    const float* W2   = (const float*)d_in[20];
    const float* b2   = (const float*)d_in[21];

    float* ws = (float*)d_ws;
    size_t off = 0;
    auto alloc_f = [&](size_t n) { float* p = ws + off; off += n; return p; };
    float* S1f  = alloc_f(524288);
    float* kh   = alloc_f(524288);
    float* vh   = alloc_f(524288);
    float* qh2  = alloc_f(524288);
    float* qhR  = alloc_f(7680);
    float* s1   = alloc_f(122880);
    float* Bm   = alloc_f(7680);
    float* kh2  = alloc_f(7680);
    float* vh2  = alloc_f(7680);
    float* Smix = alloc_f(524288);
    float* S2   = alloc_f(524288);
    float* yv   = alloc_f(2048);
    float* W1T  = alloc_f(65536);
    unsigned short* us = (unsigned short*)(ws + off);
    size_t uoff = 0;
    auto alloc_u = [&](size_t n) { unsigned short* p = us + uoff; uoff += n; return p; };
    unsigned short* H0hi[2] = { alloc_u(524288), alloc_u(524288) };
    unsigned short* H0lo[2] = { alloc_u(524288), alloc_u(524288) };
    unsigned short* H1hi[2] = { alloc_u(524288), alloc_u(524288) };
    unsigned short* H1lo[2] = { alloc_u(524288), alloc_u(524288) };
    unsigned short* FB0hi = alloc_u(245760);
    unsigned short* FB0lo = alloc_u(245760);
    unsigned short* FB1hi = alloc_u(393216);
    unsigned short* FB1lo = alloc_u(393216);
    unsigned short* FXhi  = alloc_u(16777216);

    // ---- prep: pack weights + x, zero initial states ----
    pack_w<<<960, 256, 0, stream>>>(Whh0, Wih0, 64, 320, FB0hi, FB0lo, 245760);
    pack_w<<<1536, 256, 0, stream>>>(Whh1, Wih1, 256, 512, FB1hi, FB1lo, 393216);
    pack_x<<<65536, 256, 0, stream>>>(x, FXhi);
    (void)hipMemsetAsync(H0hi[0], 0, 1048576, stream);
    (void)hipMemsetAsync(H0lo[0], 0, 1048576, stream);
    (void)hipMemsetAsync(H1hi[1], 0, 1048576, stream);
    (void)hipMemsetAsync(H1lo[1], 0, 1048576, stream);

    // ---- recurrence: launch i computes h0[i] (layer0) and h1[i-1] (layer1) ----
    for (int i = 0; i <= TT; ++i) {
        const int p = i & 1;
        gru_step<<<256, 256, 0, stream>>>(
            H0hi[p], H0lo[p], H0hi[1 - p], H0lo[1 - p],
            H1hi[p], H1lo[p], H1hi[1 - p], H1lo[1 - p],
            FXhi, FB0hi, FB0lo, FB1hi, FB1lo,
            bih0, bhh0, bih1, bhh1, S1f, i);
    }

    // ---- epilogue ----
    proj_gemm<<<192, 256, 0, stream>>>(S1f, Wk, bk, Wv, bv, Wq, bq, kh, vh, qh2);
    projR_kernel<<<30, 256, 0, stream>>>(R, Wq, bq, qhR);
    scores1_kernel<<<480, 256, 0, stream>>>(qhR, kh, s1);
    softmax1_kernel<<<60, 256, 0, stream>>>(s1);
    o1_kernel<<<60, 128, 0, stream>>>(s1, vh, Bm);
    proj3_kernel<<<60, 256, 0, stream>>>(Bm, 30, Wk, bk, Wv, bv, kh2, vh2);
    attn2_kernel<<<2048, 256, 0, stream>>>(qh2, kh2, vh2, S1f, Wg, bg, Smix);
    w1t_kernel<<<256, 256, 0, stream>>>(W1, W1T);
    mlp_kernel<<<2048, 256, 0, stream>>>(Smix, W1T, b1, S2);
    y_kernel<<<2048, 256, 0, stream>>>(S2, W2, b2, yv);
    norm_kernel<<<1, 1024, 0, stream>>>(yv, (float*)d_out);
}

// Round 5
// 3303.830 us; speedup vs baseline: 2.4048x; 2.4048x over previous
//
#include <hip/hip_runtime.h>
#include <hip/hip_bf16.h>

// CrossGRU round 5: register-direct pipelined MFMA GRU (no LDS, no barriers).
// r4 failed on the serialized global_load_lds -> vmcnt(0)-barrier pipeline (63us/step,
// 410 GB/s latency-bound). r5: frag-major packed weights/state, each wave loads its
// fragments straight to VGPRs with a 1-deep software pipeline, K-loop fully unrolled,
// 512 blocks (2/CU, 8 waves/CU). bid&7=cb -> per-XCD-stable weight slices in L2.

#define HH  256
#define TT  128
#define INP 64
#define KH  8   // h-part kc count (256/32)

typedef float f32x4 __attribute__((ext_vector_type(4)));
typedef short bf16x8 __attribute__((ext_vector_type(8)));

#define MFMA(A,B,C) __builtin_amdgcn_mfma_f32_16x16x32_bf16((A),(B),(C),0,0,0)

__device__ __forceinline__ float bf2f(unsigned short s) {
    unsigned u = ((unsigned)s) << 16;
    float f; __builtin_memcpy(&f, &u, 4); return f;
}
__device__ __forceinline__ unsigned short f2bf(float f) {
    unsigned u; __builtin_memcpy(&u, &f, 4);
    unsigned r = (u + 0x7FFFu + ((u >> 16) & 1u)) >> 16;
    return (unsigned short)r;
}

// fragment-major index for element (row r, col k), K cols:
// idx = (r>>4)*(K*16) + (k>>5)*512 + ((k>>3)&3)*128 + (r&15)*8 + (k&7)

__global__ void pack_w(const float* __restrict__ Whh, const float* __restrict__ Wih,
                       int Kin, int Kw, unsigned short* __restrict__ FBhi,
                       unsigned short* __restrict__ FBlo, int total)
{
    int idx = blockIdx.x * 256 + threadIdx.x;
    if (idx >= total) return;
    int n = idx / Kw, k = idx - n * Kw;
    float v = (k < 256) ? Whh[n * 256 + k] : Wih[n * Kin + (k - 256)];
    int dst = (n >> 4) * (Kw * 16) + (k >> 5) * 512 + ((k >> 3) & 3) * 128 + (n & 15) * 8 + (k & 7);
    unsigned short h = f2bf(v);
    FBhi[dst] = h;
    FBlo[dst] = f2bf(v - bf2f(h));
}

__global__ void pack_x(const float* __restrict__ x, unsigned short* __restrict__ FXhi)
{
    int idx = blockIdx.x * 256 + threadIdx.x;  // 2048*128*64
    int k = idx & 63;
    int t = (idx >> 6) & 127;
    int m = idx >> 13;
    int dst = t * 131072 + (m >> 4) * 1024 + (k >> 5) * 512 + ((k >> 3) & 3) * 128 + (m & 15) * 8 + (k & 7);
    FXhi[dst] = f2bf(x[idx]);
}

// ---------------- GRU step core ----------------
// wave = 32 rows (2 m-tiles) x 16 ch (1 n-tile per gate), 3-term hi/lo MFMA.
template<int NKC, bool LAY>
__device__ __forceinline__ void gru_core(
    const unsigned short* __restrict__ Ah_h, const unsigned short* __restrict__ Al_h,
    const unsigned short* __restrict__ Ah_x, const unsigned short* __restrict__ Al_x,
    const unsigned short* __restrict__ B_hi, const unsigned short* __restrict__ B_lo,
    int mt0, int ntb, int lane,
    f32x4 (&ar)[2], f32x4 (&az)[2], f32x4 (&anh)[2], f32x4 (&anx)[2])
{
    const int Kw16 = NKC * 512;            // Kw*16
    const int xs = LAY ? 4096 : 1024;      // x-source per-m-tile stride
    const int lo8 = lane * 8;
    const unsigned short* bh[3];
    const unsigned short* bl[3];
#pragma unroll
    for (int g = 0; g < 3; ++g) {
        bh[g] = B_hi + (g * 16 + ntb) * Kw16 + lo8;
        bl[g] = B_lo + (g * 16 + ntb) * Kw16 + lo8;
    }

    bf16x8 cA[2][2], cB[3][2], nA[2][2], nB[3][2];

    auto ldA = [&](int kc, bf16x8 (&A)[2][2]) {
        if (kc < KH) {
#pragma unroll
            for (int mt = 0; mt < 2; ++mt) {
                A[mt][0] = *(const bf16x8*)(Ah_h + (mt0 + mt) * 4096 + kc * 512 + lo8);
                A[mt][1] = *(const bf16x8*)(Al_h + (mt0 + mt) * 4096 + kc * 512 + lo8);
            }
        } else {
#pragma unroll
            for (int mt = 0; mt < 2; ++mt) {
                A[mt][0] = *(const bf16x8*)(Ah_x + (mt0 + mt) * xs + (kc - KH) * 512 + lo8);
                if (LAY)
                    A[mt][1] = *(const bf16x8*)(Al_x + (mt0 + mt) * xs + (kc - KH) * 512 + lo8);
            }
        }
    };
    auto ldB = [&](int kc, bf16x8 (&B)[3][2]) {
#pragma unroll
        for (int g = 0; g < 3; ++g) {
            B[g][0] = *(const bf16x8*)(bh[g] + kc * 512);
            B[g][1] = *(const bf16x8*)(bl[g] + kc * 512);
        }
    };

    ldA(0, cA); ldB(0, cB);
#pragma unroll
    for (int kc = 0; kc < NKC; ++kc) {
        if (kc + 1 < NKC) { ldA(kc + 1, nA); ldB(kc + 1, nB); }
        const bool hp = (kc < KH);
        const bool a3 = LAY || hp;     // 3rd (a_lo) term availability
#pragma unroll
        for (int mt = 0; mt < 2; ++mt) {
            ar[mt] = MFMA(cA[mt][0], cB[0][0], ar[mt]);
            ar[mt] = MFMA(cA[mt][0], cB[0][1], ar[mt]);
            if (a3) ar[mt] = MFMA(cA[mt][1], cB[0][0], ar[mt]);
            az[mt] = MFMA(cA[mt][0], cB[1][0], az[mt]);
            az[mt] = MFMA(cA[mt][0], cB[1][1], az[mt]);
            if (a3) az[mt] = MFMA(cA[mt][1], cB[1][0], az[mt]);
            if (hp) {
                anh[mt] = MFMA(cA[mt][0], cB[2][0], anh[mt]);
                anh[mt] = MFMA(cA[mt][0], cB[2][1], anh[mt]);
                if (a3) anh[mt] = MFMA(cA[mt][1], cB[2][0], anh[mt]);
            } else {
                anx[mt] = MFMA(cA[mt][0], cB[2][0], anx[mt]);
                anx[mt] = MFMA(cA[mt][0], cB[2][1], anx[mt]);
                if (a3) anx[mt] = MFMA(cA[mt][1], cB[2][0], anx[mt]);
            }
        }
#pragma unroll
        for (int mt = 0; mt < 2; ++mt) { cA[mt][0] = nA[mt][0]; cA[mt][1] = nA[mt][1]; }
#pragma unroll
        for (int g = 0; g < 3; ++g) { cB[g][0] = nB[g][0]; cB[g][1] = nB[g][1]; }
    }
}

// grid 512 x 256: blocks [0,256)=L0 step, [256,512)=L1 step-1.
// block = 64 rows x 32 ch; waves 2x2: wm row-half (32 rows), wn ch-half (16 ch).
__global__ __launch_bounds__(256) void gru_step(
    const unsigned short* __restrict__ H0rhi, const unsigned short* __restrict__ H0rlo,
    unsigned short* __restrict__ H0whi, unsigned short* __restrict__ H0wlo,
    const unsigned short* __restrict__ H1rhi, const unsigned short* __restrict__ H1rlo,
    unsigned short* __restrict__ H1whi, unsigned short* __restrict__ H1wlo,
    const unsigned short* __restrict__ FXhi,
    const unsigned short* __restrict__ FB0hi, const unsigned short* __restrict__ FB0lo,
    const unsigned short* __restrict__ FB1hi, const unsigned short* __restrict__ FB1lo,
    const float* __restrict__ bih0, const float* __restrict__ bhh0,
    const float* __restrict__ bih1, const float* __restrict__ bhh1,
    float* __restrict__ S1f, int step)
{
    const int layer = blockIdx.x >> 8;
    if (!layer && step >= TT) return;
    if (layer && step == 0) return;
    const int lbid = blockIdx.x & 255;
    const int mb = lbid >> 3;         // 64-row group (32)
    const int cb = lbid & 7;          // 32-ch group (8) == XCD id under %8 dispatch
    const int tid = threadIdx.x;
    const int w = tid >> 6, lane = tid & 63;
    const int wm = w >> 1, wn = w & 1;
    const int l15 = lane & 15, q = lane >> 4;
    const int mt0 = mb * 4 + wm * 2;  // first 16-row tile (of 128)
    const int ntb = cb * 2 + wn;      // 16-ch tile within gate (0..15)

    f32x4 ar[2], az[2], anh[2], anx[2];
#pragma unroll
    for (int i = 0; i < 2; ++i) {
        ar[i] = (f32x4){0.f,0.f,0.f,0.f}; az[i] = (f32x4){0.f,0.f,0.f,0.f};
        anh[i] = (f32x4){0.f,0.f,0.f,0.f}; anx[i] = (f32x4){0.f,0.f,0.f,0.f};
    }

    if (layer) {
        gru_core<16, true>(H1rhi, H1rlo, H0rhi, H0rlo, FB1hi, FB1lo,
                           mt0, ntb, lane, ar, az, anh, anx);
    } else {
        gru_core<10, false>(H0rhi, H0rlo, FXhi + step * 131072, (const unsigned short*)0,
                            FB0hi, FB0lo, mt0, ntb, lane, ar, az, anh, anx);
    }

    const unsigned short* Ahi_h = layer ? H1rhi : H0rhi;
    const unsigned short* Alo_h = layer ? H1rlo : H0rlo;
    unsigned short* Whi = layer ? H1whi : H0whi;
    unsigned short* Wlo = layer ? H1wlo : H0wlo;
    const float* bih = layer ? bih1 : bih0;
    const float* bhh = layer ? bhh1 : bhh0;

    const int c = (ntb << 4) + l15;   // channel 0..255
    const float brb = bih[c] + bhh[c];
    const float bzb = bih[256 + c] + bhh[256 + c];
    const float bni = bih[512 + c];
    const float bnh = bhh[512 + c];
    const int cfr = (c >> 5) * 512 + ((c >> 3) & 3) * 128 + (c & 7);
#pragma unroll
    for (int mt = 0; mt < 2; ++mt) {
        const int mtg = mt0 + mt;
        const int fbase = mtg * 4096 + cfr;
#pragma unroll
        for (int rg = 0; rg < 4; ++rg) {
            const int mi = q * 4 + rg;
            const int fidx = fbase + mi * 8;
            const float ho = bf2f(Ahi_h[fidx]) + bf2f(Alo_h[fidx]);
            const float rr = 1.f / (1.f + expf(-(ar[mt][rg] + brb)));
            const float zz = 1.f / (1.f + expf(-(az[mt][rg] + bzb)));
            const float nn = tanhf(anx[mt][rg] + bni + rr * (anh[mt][rg] + bnh));
            const float hn = (1.f - zz) * nn + zz * ho;
            const unsigned short hb = f2bf(hn);
            Whi[fidx] = hb;
            Wlo[fidx] = f2bf(hn - bf2f(hb));
            if (layer) S1f[(mtg * 16 + mi) * 256 + c] = hn;
        }
    }
}

// ---------------- epilogue (unchanged from r4) ----------------

__global__ __launch_bounds__(256) void proj_gemm(const float* __restrict__ S,
    const float* __restrict__ Wk, const float* __restrict__ bk,
    const float* __restrict__ Wv, const float* __restrict__ bv,
    const float* __restrict__ Wq, const float* __restrict__ bq,
    float* __restrict__ ok, float* __restrict__ ov, float* __restrict__ oq)
{
    __shared__ float sT[256][65];
    const int bid = blockIdx.x;            // 192 = 3p * 2h * 32lt
    const int p = bid >> 6;
    const int h = (bid >> 5) & 1;
    const int l0 = (bid & 31) * 64;
    const int tid = threadIdx.x;
    const float* W = (p == 0) ? Wk : ((p == 1) ? Wv : Wq);
    const float* b = (p == 0) ? bk : ((p == 1) ? bv : bq);
    float* o = (p == 0) ? ok : ((p == 1) ? ov : oq);

    for (int e = tid; e < 64 * 256; e += 256) {
        int k = e & 255, l = e >> 8;
        sT[k][l] = S[(l0 + l) * 256 + k];
    }
    __syncthreads();

    const int dg = tid & 15, lg = tid >> 4;
    const int d0 = dg * 8;
    const float* Wp = W + h * 32768 + d0;
    float acc[4][8];
#pragma unroll
    for (int i = 0; i < 4; ++i)
#pragma unroll
        for (int j = 0; j < 8; ++j) acc[i][j] = 0.f;

    for (int k = 0; k < 256; ++k) {
        f32x4 sv = *(const f32x4*)&sT[k][lg * 4];
        f32x4 w0 = *(const f32x4*)(Wp + k * 128);
        f32x4 w1 = *(const f32x4*)(Wp + k * 128 + 4);
#pragma unroll
        for (int i = 0; i < 4; ++i) {
#pragma unroll
            for (int j = 0; j < 4; ++j) {
                acc[i][j]     += sv[i] * w0[j];
                acc[i][4 + j] += sv[i] * w1[j];
            }
        }
    }
#pragma unroll
    for (int i = 0; i < 4; ++i) {
        float* op = o + (h * 2048 + l0 + lg * 4 + i) * 128 + d0;
#pragma unroll
        for (int j = 0; j < 8; ++j) op[j] = acc[i][j] + b[h * 128 + d0 + j];
    }
}

__global__ void proj3_kernel(const float* __restrict__ A, int M,
    const float* __restrict__ Wk, const float* __restrict__ bk,
    const float* __restrict__ Wv, const float* __restrict__ bv,
    float* __restrict__ ok, float* __restrict__ ov)
{
    int idx = blockIdx.x * 256 + threadIdx.x;
    if (idx >= 2 * 2 * M * 128) return;
    int d = idx & 127;
    int rest = idx >> 7;
    int l = rest % M;
    int ph = rest / M;
    int h = ph & 1, p = ph >> 1;
    const float* W = (p == 0) ? Wk : Wv;
    const float* b = (p == 0) ? bk : bv;
    float* o = (p == 0) ? ok : ov;
    float accv = b[h * 128 + d];
    const float* a = A + l * 256;
    const float* wp = W + h * (256 * 128) + d;
    for (int j = 0; j < 256; ++j) accv += a[j] * wp[j * 128];
    o[(h * M + l) * 128 + d] = accv;
}

__global__ void projR_kernel(const float* __restrict__ R,
    const float* __restrict__ Wq, const float* __restrict__ bq,
    float* __restrict__ oq)
{
    int idx = blockIdx.x * 256 + threadIdx.x;
    if (idx >= 2 * 30 * 128) return;
    int d = idx & 127;
    int rest = idx >> 7;
    int l = rest % 30;
    int h = rest / 30;
    float a = bq[h * 128 + d];
    const float* r = R + l * 256;
    const float* wp = Wq + h * 32768 + d;
    for (int j = 0; j < 256; ++j) a += r[j] * wp[j * 128];
    oq[(h * 30 + l) * 128 + d] = a;
}

__global__ void scores1_kernel(const float* __restrict__ qhR, const float* __restrict__ kh,
                               float* __restrict__ s1)
{
    int idx = blockIdx.x * 256 + threadIdx.x;
    if (idx >= 2 * 30 * 2048) return;
    int k = idx & 2047;
    int rest = idx >> 11;
    int i = rest % 30;
    int h = rest / 30;
    const f32x4* qp = (const f32x4*)(qhR + (h * 30 + i) * 128);
    const f32x4* kp = (const f32x4*)(kh + (h * 2048 + k) * 128);
    float acc = 0.f;
    for (int dd = 0; dd < 32; ++dd) {
        f32x4 a = qp[dd], b = kp[dd];
        acc += a[0] * b[0] + a[1] * b[1] + a[2] * b[2] + a[3] * b[3];
    }
    s1[idx] = acc * 0.08838834764831845f;
}

__global__ void softmax1_kernel(float* __restrict__ s1)
{
    __shared__ float red[256];
    float* p = s1 + blockIdx.x * 2048;
    int tid = threadIdx.x;
    float mx = -1e30f;
    for (int k = tid; k < 2048; k += 256) mx = fmaxf(mx, p[k]);
    red[tid] = mx; __syncthreads();
    for (int s = 128; s > 0; s >>= 1) { if (tid < s) red[tid] = fmaxf(red[tid], red[tid + s]); __syncthreads(); }
    mx = red[0]; __syncthreads();
    float sum = 0.f;
    for (int k = tid; k < 2048; k += 256) { float e = expf(p[k] - mx); p[k] = e; sum += e; }
    red[tid] = sum; __syncthreads();
    for (int s = 128; s > 0; s >>= 1) { if (tid < s) red[tid] += red[tid + s]; __syncthreads(); }
    float inv = 1.f / red[0];
    for (int k = tid; k < 2048; k += 256) p[k] *= inv;
}

__global__ void o1_kernel(const float* __restrict__ p1, const float* __restrict__ vh,
                          float* __restrict__ Bm)
{
    int row = blockIdx.x;            // h*30+i
    int h = row / 30;
    int i = row % 30;
    int d = threadIdx.x;             // 128
    const float* pp = p1 + row * 2048;
    const float* vp = vh + h * 2048 * 128 + d;
    float acc = 0.f;
    for (int k = 0; k < 2048; ++k) acc += pp[k] * vp[k * 128];
    Bm[i * 256 + h * 128 + d] = acc;
}

__global__ __launch_bounds__(256) void attn2_kernel(
    const float* __restrict__ qh2, const float* __restrict__ kh2, const float* __restrict__ vh2,
    const float* __restrict__ S, const float* __restrict__ Wg,
    const float* __restrict__ bg, float* __restrict__ Smix)
{
    __shared__ float ks[2 * 30 * 129];
    __shared__ float qred[256];
    __shared__ float ps[64];
    int l = blockIdx.x;
    int tid = threadIdx.x;
    for (int idx = tid; idx < 2 * 30 * 128; idx += 256) {
        int hh = idx / 3840; int rem = idx - hh * 3840;
        int j = rem >> 7; int d = rem & 127;
        ks[(hh * 30 + j) * 129 + d] = kh2[idx];
    }
    int h = tid >> 7, d = tid & 127;
    qred[tid] = qh2[(h * 2048 + l) * 128 + d];
    __syncthreads();
    int w = tid >> 6, lane = tid & 63;
    if (w < 2 && lane < 32) {
        float sc = -1e30f;
        if (lane < 30) {
            const float* qp = qred + w * 128;
            float a = 0.f;
            for (int dd = 0; dd < 128; ++dd) a += qp[dd] * ks[(w * 30 + lane) * 129 + dd];
            sc = a * 0.08838834764831845f;
        }
        float mx = sc;
        for (int m = 16; m > 0; m >>= 1) mx = fmaxf(mx, __shfl_xor(mx, m, 32));
        float e = (lane < 30) ? expf(sc - mx) : 0.f;
        float sm = e;
        for (int m = 16; m > 0; m >>= 1) sm += __shfl_xor(sm, m, 32);
        ps[w * 32 + lane] = e / sm;
    }
    __syncthreads();
    float o = 0.f;
    const float* vp = vh2 + h * 3840 + d;
    for (int j = 0; j < 30; ++j) o += ps[h * 32 + j] * vp[j * 128];
    float sl = S[l * 256 + tid];
    qred[tid] = sl * Wg[tid];
    __syncthreads();
    for (int s = 128; s > 0; s >>= 1) { if (tid < s) qred[tid] += qred[tid + s]; __syncthreads(); }
    float alpha = 1.f / (1.f + expf(-(qred[0] + bg[0])));
    Smix[l * 256 + tid] = alpha * o + (1.f - alpha) * sl;
}

__global__ void w1t_kernel(const float* __restrict__ W1, float* __restrict__ W1T)
{
    int idx = blockIdx.x * 256 + threadIdx.x;  // 65536
    int j = idx & 255, c = idx >> 8;
    W1T[j * 256 + c] = W1[c * 256 + j];
}

__global__ void mlp_kernel(const float* __restrict__ Smix, const float* __restrict__ W1T,
                           const float* __restrict__ b1, float* __restrict__ S2)
{
    int idx = blockIdx.x * 256 + threadIdx.x;  // l*256+c
    int c = idx & 255; int l = idx >> 8;
    const float* a = Smix + l * 256;
    float acc = b1[c];
    for (int j = 0; j < 256; ++j) acc += a[j] * W1T[j * 256 + c];
    float v = fmaxf(acc, 0.f);
    S2[idx] = v + a[c];
}

__global__ void y_kernel(const float* __restrict__ S2, const float* __restrict__ W2,
                         const float* __restrict__ b2, float* __restrict__ y)
{
    __shared__ float red[256];
    int l = blockIdx.x; int tid = threadIdx.x;
    red[tid] = S2[l * 256 + tid] * W2[tid];
    __syncthreads();
    for (int s = 128; s > 0; s >>= 1) { if (tid < s) red[tid] += red[tid + s]; __syncthreads(); }
    if (tid == 0) y[l] = red[0] + b2[0];
}

__global__ void norm_kernel(const float* __restrict__ y, float* __restrict__ out)
{
    __shared__ float r1[1024], r2[1024];
    int tid = threadIdx.x;
    float s1v = 0.f, s2v = 0.f;
    for (int idx = tid; idx < 2048; idx += 1024) { float v = y[idx]; s1v += v; s2v += v * v; }
    r1[tid] = s1v; r2[tid] = s2v; __syncthreads();
    for (int s = 512; s > 0; s >>= 1) {
        if (tid < s) { r1[tid] += r1[tid + s]; r2[tid] += r2[tid + s]; }
        __syncthreads();
    }
    float mean = r1[0] / 2048.f;
    float var = fmaxf((r2[0] - 2048.f * mean * mean) / 2047.f, 0.f);
    float inv = 1.f / (sqrtf(var) + 1e-8f);
    for (int idx = tid; idx < 2048; idx += 1024)
        out[idx] = (y[idx] - mean) * inv;
}

extern "C" void kernel_launch(void* const* d_in, const int* in_sizes, int n_in,
                              void* d_out, int out_size, void* d_ws, size_t ws_size,
                              hipStream_t stream)
{
    const float* x    = (const float*)d_in[0];
    const float* Wih0 = (const float*)d_in[1];
    const float* Whh0 = (const float*)d_in[2];
    const float* bih0 = (const float*)d_in[3];
    const float* bhh0 = (const float*)d_in[4];
    const float* Wih1 = (const float*)d_in[5];
    const float* Whh1 = (const float*)d_in[6];
    const float* bih1 = (const float*)d_in[7];
    const float* bhh1 = (const float*)d_in[8];
    const float* Wq   = (const float*)d_in[9];
    const float* bq   = (const float*)d_in[10];
    const float* Wk   = (const float*)d_in[11];
    const float* bk   = (const float*)d_in[12];
    const float* Wv   = (const float*)d_in[13];
    const float* bv   = (const float*)d_in[14];
    const float* R    = (const float*)d_in[15];
    const float* Wg   = (const float*)d_in[16];
    const float* bg   = (const float*)d_in[17];
    const float* W1   = (const float*)d_in[18];
    const float* b1   = (const float*)d_in[19];
    const float* W2   = (const float*)d_in[20];
    const float* b2   = (const float*)d_in[21];

    float* ws = (float*)d_ws;
    size_t off = 0;
    auto alloc_f = [&](size_t n) { float* p = ws + off; off += n; return p; };
    float* S1f  = alloc_f(524288);
    float* kh   = alloc_f(524288);
    float* vh   = alloc_f(524288);
    float* qh2  = alloc_f(524288);
    float* qhR  = alloc_f(7680);
    float* s1   = alloc_f(122880);
    float* Bm   = alloc_f(7680);
    float* kh2  = alloc_f(7680);
    float* vh2  = alloc_f(7680);
    float* Smix = alloc_f(524288);
    float* S2   = alloc_f(524288);
    float* yv   = alloc_f(2048);
    float* W1T  = alloc_f(65536);
    unsigned short* us = (unsigned short*)(ws + off);
    size_t uoff = 0;
    auto alloc_u = [&](size_t n) { unsigned short* p = us + uoff; uoff += n; return p; };
    unsigned short* H0hi[2] = { alloc_u(524288), alloc_u(524288) };
    unsigned short* H0lo[2] = { alloc_u(524288), alloc_u(524288) };
    unsigned short* H1hi[2] = { alloc_u(524288), alloc_u(524288) };
    unsigned short* H1lo[2] = { alloc_u(524288), alloc_u(524288) };
    unsigned short* FB0hi = alloc_u(245760);
    unsigned short* FB0lo = alloc_u(245760);
    unsigned short* FB1hi = alloc_u(393216);
    unsigned short* FB1lo = alloc_u(393216);
    unsigned short* FXhi  = alloc_u(16777216);

    pack_w<<<960, 256, 0, stream>>>(Whh0, Wih0, 64, 320, FB0hi, FB0lo, 245760);
    pack_w<<<1536, 256, 0, stream>>>(Whh1, Wih1, 256, 512, FB1hi, FB1lo, 393216);
    pack_x<<<65536, 256, 0, stream>>>(x, FXhi);
    (void)hipMemsetAsync(H0hi[0], 0, 1048576, stream);
    (void)hipMemsetAsync(H0lo[0], 0, 1048576, stream);
    (void)hipMemsetAsync(H1hi[1], 0, 1048576, stream);
    (void)hipMemsetAsync(H1lo[1], 0, 1048576, stream);

    for (int i = 0; i <= TT; ++i) {
        const int p = i & 1;
        gru_step<<<512, 256, 0, stream>>>(
            H0hi[p], H0lo[p], H0hi[1 - p], H0lo[1 - p],
            H1hi[p], H1lo[p], H1hi[1 - p], H1lo[1 - p],
            FXhi, FB0hi, FB0lo, FB1hi, FB1lo,
            bih0, bhh0, bih1, bhh1, S1f, i);
    }

    proj_gemm<<<192, 256, 0, stream>>>(S1f, Wk, bk, Wv, bv, Wq, bq, kh, vh, qh2);
    projR_kernel<<<30, 256, 0, stream>>>(R, Wq, bq, qhR);
    scores1_kernel<<<480, 256, 0, stream>>>(qhR, kh, s1);
    softmax1_kernel<<<60, 256, 0, stream>>>(s1);
    o1_kernel<<<60, 128, 0, stream>>>(s1, vh, Bm);
    proj3_kernel<<<60, 256, 0, stream>>>(Bm, 30, Wk, bk, Wv, bv, kh2, vh2);
    attn2_kernel<<<2048, 256, 0, stream>>>(qh2, kh2, vh2, S1f, Wg, bg, Smix);
    w1t_kernel<<<256, 256, 0, stream>>>(W1, W1T);
    mlp_kernel<<<2048, 256, 0, stream>>>(Smix, W1T, b1, S2);
    y_kernel<<<2048, 256, 0, stream>>>(S2, W2, b2, yv);
    norm_kernel<<<1, 1024, 0, stream>>>(yv, (float*)d_out);
}